// Round 8
// baseline (772.736 us; speedup 1.0000x reference)
//
#include <hip/hip_runtime.h>

typedef unsigned short u16;
typedef unsigned int   u32;
typedef __attribute__((ext_vector_type(4)))  u16   us4;
typedef __attribute__((ext_vector_type(8)))  u16   us8;
typedef __attribute__((ext_vector_type(8)))  short s8v;
typedef __attribute__((ext_vector_type(16))) float f32x16;

#define L_   2048
#define D_   512
#define H_   8
#define PE_  2097152ull      // B*L*D elements of one fp32 projection array

// ---- ws layout (bytes) ----
//  [0 .. 32MB)    : 8 bf16 mats (QRH,QRL,QIH,QIL,KRH,KRL,KIH,KIL), each [bh][i][64]
//  [32 .. 40MB)   : 2 bf16 mats VTR,VTI, each [bh][dh][2048] (V transposed)
//  [40 .. 56.6MB) : O partials bf16 [4096][512]: POR0,POR1,POI0,POI1
//  [56.6MB ..)    : MH0,MH1,LH0,LH1,G0,G1  (each 32768 f32)
#define MATE    2097152ull   // u16 elems per mat
#define BHE     131072u      // u16 elems per (bh) slice of a mat (2048*64)
#define VT_OFF  33554432ull
#define POR0_OFF 41943040ull
#define POR1_OFF 46137344ull
#define POI0_OFF 50331648ull
#define POI1_OFF 54525952ull
#define MH0_OFF  58720256ull
#define MH1_OFF  58851328ull
#define LH0_OFF  58982400ull
#define LH1_OFF  59113472ull
#define G0_OFF   59244544ull
#define G1_OFF   59375616ull

// ---- d_out scratch (bytes from out base; inside attnbuf, dead before attn writes) ----
#define XRH_O 16777216ull
#define XRL_O 20971520ull
#define XIH_O 25165824ull
#define XIL_O 29360128ull

#define MFMA32(a,b,c) __builtin_amdgcn_mfma_f32_32x32x16_bf16(a,b,c,0,0,0)
#define ROWOF(r,hi) (((r)&3) + 8*((r)>>2) + 4*(hi))

__device__ __forceinline__ u16 f2bf(float x){
    u32 u = __float_as_uint(x);
    u += 0x7FFFu + ((u>>16)&1u);
    return (u16)(u>>16);
}
__device__ __forceinline__ float bf2f(u16 h){ return __uint_as_float(((u32)h)<<16); }

// ============================================================
// Prep: split wave_real / wave_imag into bf16 hi/lo mats (d_out scratch)
// ============================================================
__global__ __launch_bounds__(256)
void split_prep_kernel(const float* __restrict__ wr, const float* __restrict__ wi,
                       unsigned char* __restrict__ outb)
{
    const int z = blockIdx.y;
    const float* src = z ? wi : wr;
    u16* hg = (u16*)(outb + (z ? XIH_O : XRH_O));
    u16* lg = (u16*)(outb + (z ? XIL_O : XRL_O));
    const size_t idx4 = ((size_t)blockIdx.x * 256 + threadIdx.x) * 4;
    float4 v = *(const float4*)&src[idx4];
    float vv[4] = { v.x, v.y, v.z, v.w };
    us4 h, l;
    #pragma unroll
    for (int c = 0; c < 4; ++c) {
        u16 hb = f2bf(vv[c]);
        h[c] = hb;
        l[c] = f2bf(vv[c] - bf2f(hb));
    }
    *(us4*)&hg[idx4] = h;
    *(us4*)&lg[idx4] = l;
}

// ============================================================
// LDS helpers (XOR swizzle byte ^= (row&7)<<4, both sides)
// ============================================================
__device__ __forceinline__ s8v ldfrag(const unsigned char* Lp, u32 matOff, u32 row, u32 colb)
{
    return *(const s8v*)(Lp + matOff + row*128u + (colb ^ ((row&7u)<<4)));
}
__device__ __forceinline__ void stage_qk(unsigned char* Lp, u32 matOff,
                                         const u16* __restrict__ g, int rowBase, int tid)
{
    const int ch = tid & 7;
    const int r0 = tid >> 3;
    #pragma unroll
    for (int rr = 0; rr < 2; ++rr) {
        u32 row = rr*32 + r0;
        us8 v = ((const us8*)(g + (size_t)(rowBase + row)*64))[ch];
        *(us8*)(Lp + matOff + row*128u + (((u32)ch<<4) ^ ((row&7u)<<4))) = v;
    }
}
__device__ __forceinline__ void stage_vt(unsigned char* Lp, u32 matOff,
                                         const u16* __restrict__ g, int j0, int tid)
{
    const int ch = tid & 7;
    const int r0 = tid >> 3;
    #pragma unroll
    for (int rr = 0; rr < 2; ++rr) {
        u32 dh = rr*32 + r0;
        us8 v = ((const us8*)(g + (size_t)dh*2048 + j0))[ch];
        *(us8*)(Lp + matOff + dh*128u + (((u32)ch<<4) ^ ((dh&7u)<<4))) = v;
    }
}

// ============================================================
// MFMA projection: C = X @ W^T + b for 6 combos. (unchanged, proven)
// ============================================================
__global__ __launch_bounds__(256, 2)
void proj_mfma_kernel(const unsigned char* __restrict__ scr,
                      const float* __restrict__ Wq, const float* __restrict__ Wk,
                      const float* __restrict__ Wv,
                      const float* __restrict__ bq, const float* __restrict__ bk,
                      const float* __restrict__ bv,
                      u16* __restrict__ qk, u16* __restrict__ vt)
{
    const int z = blockIdx.z;
    const u16* Ah_g = (const u16*)(scr + ((z & 1) ? XIH_O : XRH_O));
    const u16* Al_g = (const u16*)(scr + ((z & 1) ? XIL_O : XRL_O));
    const int wsel = z >> 1;
    const float* Wf; const float* bias;
    if (wsel == 0)      { Wf = Wq; bias = bq; }
    else if (wsel == 1) { Wf = Wk; bias = bk; }
    else                { Wf = Wv; bias = bv; }
    const bool four = (wsel < 2);

    const int m0 = blockIdx.x * 128;
    const int n0 = blockIdx.y * 64;

    __shared__ __align__(16) unsigned char L[49152];
    enum : u32 { AH=0, AL=16384, BH=32768, BL=40960 };

    const int tid  = threadIdx.x;
    const int lane = tid & 63;
    const int wid  = tid >> 6;
    const int wr   = wid >> 1, wc = wid & 1;
    const int l31  = lane & 31;
    const int hi   = lane >> 5;
    const u32 rowA0 = (u32)(wr*64 + l31);
    const u32 rowB  = (u32)(wc*32 + l31);

    f32x16 c0, c1;
    #pragma unroll
    for (int r = 0; r < 16; ++r) { c0[r] = 0.f; c1[r] = 0.f; }

    const int ch = tid & 7, r0 = tid >> 3;

    for (int k0 = 0; k0 < 512; k0 += 64) {
        __syncthreads();
        #pragma unroll
        for (int rr = 0; rr < 4; ++rr) {
            u32 row = (u32)(rr*32 + r0);
            u32 dst = row*128u + (((u32)ch<<4) ^ ((row&7u)<<4));
            us8 vh = *(const us8*)(Ah_g + (size_t)(m0 + row)*512 + k0 + ch*8);
            *(us8*)(L + AH + dst) = vh;
            if (four) {
                us8 vl = *(const us8*)(Al_g + (size_t)(m0 + row)*512 + k0 + ch*8);
                *(us8*)(L + AL + dst) = vl;
            }
        }
        #pragma unroll
        for (int rr = 0; rr < 2; ++rr) {
            u32 row = (u32)(rr*32 + r0);
            const float* src = Wf + (size_t)(n0 + row)*512 + k0 + ch*8;
            float4 v0 = *(const float4*)src;
            float4 v1 = *(const float4*)(src + 4);
            float vv[8] = { v0.x,v0.y,v0.z,v0.w, v1.x,v1.y,v1.z,v1.w };
            us8 hv, lv;
            #pragma unroll
            for (int j = 0; j < 8; ++j) {
                u16 hb = f2bf(vv[j]);
                hv[j] = hb;
                lv[j] = f2bf(vv[j] - bf2f(hb));
            }
            u32 dst = row*128u + (((u32)ch<<4) ^ ((row&7u)<<4));
            *(us8*)(L + BH + dst) = hv;
            if (four) *(us8*)(L + BL + dst) = lv;
        }
        __syncthreads();

        #pragma unroll
        for (int ks = 0; ks < 4; ++ks) {
            u32 colb = (u32)(ks*32 + hi*16);
            s8v a0h = ldfrag(L, AH, rowA0,      colb);
            s8v a1h = ldfrag(L, AH, rowA0 + 32, colb);
            s8v bh_ = ldfrag(L, BH, rowB,       colb);
            c0 = MFMA32(a0h, bh_, c0);
            c1 = MFMA32(a1h, bh_, c1);
            if (four) {
                s8v a0l = ldfrag(L, AL, rowA0,      colb);
                s8v a1l = ldfrag(L, AL, rowA0 + 32, colb);
                s8v bl_ = ldfrag(L, BL, rowB,       colb);
                c0 = MFMA32(a0h, bl_, c0); c0 = MFMA32(a0l, bh_, c0); c0 = MFMA32(a0l, bl_, c0);
                c1 = MFMA32(a1h, bl_, c1); c1 = MFMA32(a1l, bh_, c1); c1 = MFMA32(a1l, bl_, c1);
            }
        }
    }

    const int n  = n0 + wc*32 + l31;
    const float bvv = bias[n];
    const int h  = n >> 6, dh = n & 63;

    if (z < 4) {
        u16* hg = qk + (size_t)(2*z)   * MATE;
        u16* lg = qk + (size_t)(2*z+1) * MATE;
        #pragma unroll
        for (int f = 0; f < 2; ++f) {
            const f32x16& c = f ? c1 : c0;
            #pragma unroll
            for (int r = 0; r < 16; ++r) {
                int m  = m0 + wr*64 + 32*f + ROWOF(r, hi);
                int b_ = m >> 11, i = m & 2047;
                size_t idx = (size_t)(b_*8 + h)*BHE + (size_t)i*64 + dh;
                float v = c[r] + bvv;
                u16 hb = f2bf(v);
                hg[idx] = hb;
                lg[idx] = f2bf(v - bf2f(hb));
            }
        }
    } else {
        u16* vg = vt + (size_t)(z & 1) * MATE;
        #pragma unroll
        for (int f = 0; f < 2; ++f) {
            const f32x16& c = f ? c1 : c0;
            #pragma unroll
            for (int g = 0; g < 4; ++g) {
                int mb = m0 + wr*64 + 32*f + 8*g + 4*hi;
                int b_ = mb >> 11, ib = mb & 2047;
                us4 pv;
                #pragma unroll
                for (int j = 0; j < 4; ++j) pv[j] = f2bf(c[4*g + j] + bvv);
                *(us4*)&vg[(size_t)(b_*8 + h)*BHE + (size_t)dh*2048 + ib] = pv;
            }
        }
    }
}

// ============================================================
// MFMA attention, j-split halves. Block = (bh, itile, jhalf).
// Per block: 16 j-tiles. sweep1 (hi*hi QK) -> per-half m_h; sweep2
// (3-term QK) -> unnorm e -> attnbuf, P bf16 -> LDS, PV -> O partial
// (bf16, unnormalized). LDS overlay: V over K[0:16K], P over K[16K:32K]
// => 32.8 KB, 3 blocks/CU. Merge (exact algebra) happens downstream.
// ============================================================
__global__ __launch_bounds__(256, 3)
void attn_mfma_kernel(const u16* __restrict__ qk,
                      const u16* __restrict__ vt,
                      float* __restrict__ attnbuf,
                      u16* __restrict__ por0, u16* __restrict__ por1,
                      u16* __restrict__ poi0, u16* __restrict__ poi1,
                      float* __restrict__ mh0, float* __restrict__ mh1,
                      float* __restrict__ lh0, float* __restrict__ lh1)
{
    const int bh = blockIdx.x;
    const int i0 = blockIdx.y * 64;
    const int jh = blockIdx.z;
    const int jbase = jh * 16;           // first j-tile index of this half
    const int tid  = threadIdx.x;
    const int lane = tid & 63;
    const int wid  = tid >> 6;
    const int wr   = wid >> 1, wc = wid & 1;
    const int l31  = lane & 31;
    const int hi   = lane >> 5;
    const u32 rowA = wr*32 + l31;
    const u32 rowB = wc*32 + l31;

    u16* por = jh ? por1 : por0;
    u16* poi = jh ? poi1 : poi0;
    float* mh_g = jh ? mh1 : mh0;
    float* lh_g = jh ? lh1 : lh0;

    __shared__ __align__(16) unsigned char L[32768];
    __shared__ float xsc[192];           // [0:128) per-wc scratch, [128:192) combined m
    enum : u32 { KRH=0, KRL=8192, KIH=16384, KIL=24576,
                 VRo=0, VIo=8192, PAC=16384, PAS=24576 };

    const u16* qrh = qk + 0*MATE + (size_t)bh*BHE;
    const u16* qrl = qk + 1*MATE + (size_t)bh*BHE;
    const u16* qih = qk + 2*MATE + (size_t)bh*BHE;
    const u16* qil = qk + 3*MATE + (size_t)bh*BHE;
    const u16* krh = qk + 4*MATE + (size_t)bh*BHE;
    const u16* krl = qk + 5*MATE + (size_t)bh*BHE;
    const u16* kih = qk + 6*MATE + (size_t)bh*BHE;
    const u16* kil = qk + 7*MATE + (size_t)bh*BHE;
    const u16* vtr = vt + 0*MATE + (size_t)bh*BHE;
    const u16* vti = vt + 1*MATE + (size_t)bh*BHE;

    // ---- stage Q into K region; lift frags to registers ----
    stage_qk(L, KRH, qrh, i0, tid);
    stage_qk(L, KRL, qrl, i0, tid);
    stage_qk(L, KIH, qih, i0, tid);
    stage_qk(L, KIL, qil, i0, tid);
    __syncthreads();
    s8v qf[4][4];
    #pragma unroll
    for (int ks = 0; ks < 4; ++ks) {
        u32 colb = (u32)(ks*32 + hi*16);
        qf[0][ks] = ldfrag(L, KRH, rowA, colb);
        qf[1][ks] = ldfrag(L, KRL, rowA, colb);
        qf[2][ks] = ldfrag(L, KIH, rowA, colb);
        qf[3][ks] = ldfrag(L, KIL, rowA, colb);
    }

    // ---------------- sweep 1: approx per-half row max (hi*hi) ----------------
    float mx[16];
    #pragma unroll
    for (int r = 0; r < 16; ++r) mx[r] = 0.f;

    for (int jt = 0; jt < 16; ++jt) {
        __syncthreads();                       // prev reads done (or Q lift)
        stage_qk(L, KRH, krh, (jbase + jt)*64, tid);
        stage_qk(L, KIH, kih, (jbase + jt)*64, tid);
        __syncthreads();
        f32x16 ir, ii;
        #pragma unroll
        for (int r = 0; r < 16; ++r) { ir[r]=0.f; ii[r]=0.f; }
        __builtin_amdgcn_s_setprio(1);
        #pragma unroll
        for (int ks = 0; ks < 4; ++ks) {
            u32 colb = (u32)(ks*32 + hi*16);
            s8v bR = ldfrag(L, KRH, rowB, colb);
            s8v bI = ldfrag(L, KIH, rowB, colb);
            s8v nq2 = qf[2][ks] ^ (short)0x8000;
            ir = MFMA32(qf[0][ks], bR, ir);
            ir = MFMA32(qf[2][ks], bI, ir);
            ii = MFMA32(qf[0][ks], bI, ii);
            ii = MFMA32(nq2,       bR, ii);
        }
        __builtin_amdgcn_s_setprio(0);
        #pragma unroll
        for (int r = 0; r < 16; ++r)
            mx[r] = fmaxf(mx[r], fmaf(ir[r], ir[r], ii[r]*ii[r]) * 0.125f);
    }
    #pragma unroll
    for (int m = 1; m < 32; m <<= 1)
        #pragma unroll
        for (int r = 0; r < 16; ++r) mx[r] = fmaxf(mx[r], __shfl_xor(mx[r], m));

    __syncthreads();                           // last sweep1 LDS reads done
    if (l31 == 0) {
        #pragma unroll
        for (int r = 0; r < 16; ++r)
            xsc[(wr*32 + ROWOF(r,hi))*2 + wc] = mx[r];
    }
    __syncthreads();
    if (wc == 0 && l31 == 0) {
        #pragma unroll
        for (int r = 0; r < 16; ++r) {
            u32 row = wr*32 + ROWOF(r,hi);
            float mh_ = fmaxf(xsc[row*2], xsc[row*2 + 1]);
            xsc[128 + row] = mh_;
            mh_g[(size_t)bh*2048 + i0 + row] = mh_;
        }
    }
    // xsc[128..] reads happen after sweep2's in-loop barriers (ordered)

    // ---------------- sweep 2 ----------------
    f32x16 ore, oim;
    float lp[16];
    #pragma unroll
    for (int r = 0; r < 16; ++r) { ore[r]=0.f; oim[r]=0.f; lp[r]=0.f; }

    for (int jt = 0; jt < 16; ++jt) {
        const int j0 = (jbase + jt) * 64;
        __syncthreads();                       // #1: prev PV done -> K/V/P free
        stage_qk(L, KRH, krh, j0, tid);
        stage_qk(L, KRL, krl, j0, tid);
        stage_qk(L, KIH, kih, j0, tid);
        stage_qk(L, KIL, kil, j0, tid);
        __syncthreads();                       // #2: K staged
        f32x16 ir, ii;
        #pragma unroll
        for (int r = 0; r < 16; ++r) { ir[r]=0.f; ii[r]=0.f; }
        __builtin_amdgcn_s_setprio(1);
        #pragma unroll
        for (int ks = 0; ks < 4; ++ks) {
            u32 colb = (u32)(ks*32 + hi*16);
            s8v bRH = ldfrag(L, KRH, rowB, colb);
            s8v bRL = ldfrag(L, KRL, rowB, colb);
            s8v bIH = ldfrag(L, KIH, rowB, colb);
            s8v bIL = ldfrag(L, KIL, rowB, colb);
            s8v nq2 = qf[2][ks] ^ (short)0x8000;
            s8v nq3 = qf[3][ks] ^ (short)0x8000;
            ir = MFMA32(qf[0][ks], bRH, ir); ir = MFMA32(qf[0][ks], bRL, ir); ir = MFMA32(qf[1][ks], bRH, ir);
            ir = MFMA32(qf[2][ks], bIH, ir); ir = MFMA32(qf[2][ks], bIL, ir); ir = MFMA32(qf[3][ks], bIH, ir);
            ii = MFMA32(qf[0][ks], bIH, ii); ii = MFMA32(qf[0][ks], bIL, ii); ii = MFMA32(qf[1][ks], bIH, ii);
            ii = MFMA32(nq2,       bRH, ii); ii = MFMA32(nq2,       bRL, ii); ii = MFMA32(nq3,       bRH, ii);
        }
        __builtin_amdgcn_s_setprio(0);
        __syncthreads();                       // #3: K reads done -> V/P may overwrite
        stage_vt(L, VRo, vtr, j0, tid);
        stage_vt(L, VIo, vti, j0, tid);

        // pointwise: unnormalized e -> attnbuf; P bf16 -> LDS
        float* arow = attnbuf + (size_t)bh*4194304ull + (size_t)i0*2048 + j0 + wc*32 + l31;
        #pragma unroll
        for (int r = 0; r < 16; ++r) {
            u32 rowloc = wr*32 + ROWOF(r,hi);
            float xr = ir[r], xi = ii[r];
            float q  = fmaf(xr, xr, xi*xi);
            float e  = __expf(fmaf(q, 0.125f, -xsc[128 + rowloc]));
            lp[r] += e;
            float iv = rsqrtf(fmaxf(q, 1e-37f));
            float cc = xr * iv;
            float ss = xi * iv;
            arow[(size_t)rowloc*2048] = e;
            u32 colb2 = (wc*32 + l31)*2;
            *(u16*)(L + PAC + rowloc*128u + (colb2 ^ ((rowloc&7u)<<4))) = f2bf(e*cc);
            *(u16*)(L + PAS + rowloc*128u + (colb2 ^ ((rowloc&7u)<<4))) = f2bf(e*ss);
        }
        __syncthreads();                       // #4: V,P visible

        __builtin_amdgcn_s_setprio(1);
        #pragma unroll
        for (int ks = 0; ks < 4; ++ks) {
            u32 colb = (u32)(ks*32 + hi*16);
            s8v aC = ldfrag(L, PAC, rowA, colb);
            s8v aS = ldfrag(L, PAS, rowA, colb);
            s8v vR = ldfrag(L, VRo, rowB, colb);
            s8v vI = ldfrag(L, VIo, rowB, colb);
            s8v vN = vI ^ (short)0x8000;       // -Vi
            ore = MFMA32(aC, vR, ore); ore = MFMA32(aS, vN, ore);
            oim = MFMA32(aS, vR, oim); oim = MFMA32(aC, vI, oim);
        }
        __builtin_amdgcn_s_setprio(0);
    }

    // ---------------- epilogue: l_h, O partials (unnormalized) ----------------
    #pragma unroll
    for (int m = 1; m < 32; m <<= 1)
        #pragma unroll
        for (int r = 0; r < 16; ++r) lp[r] += __shfl_xor(lp[r], m);

    __syncthreads();                           // last PV done; xsc[0:128) free
    if (l31 == 0) {
        #pragma unroll
        for (int r = 0; r < 16; ++r)
            xsc[(wr*32 + ROWOF(r,hi))*2 + wc] = lp[r];
    }
    __syncthreads();

    const int b_ = bh >> 3, h = bh & 7;
    const size_t cb = (size_t)h*64 + wc*32 + l31;
    #pragma unroll
    for (int r = 0; r < 16; ++r) {
        u32 row = wr*32 + ROWOF(r,hi);
        if (wc == 0 && l31 == 0)
            lh_g[(size_t)bh*2048 + i0 + row] = xsc[row*2] + xsc[row*2 + 1];
        size_t idx = ((size_t)b_*2048 + i0 + row)*512 + cb;
        por[idx] = f2bf(ore[r]);
        poi[idx] = f2bf(oim[r]);
    }
}

// ============================================================
// merge factors: g_h = exp(m_h - m) / l   (m = max, l = merged sum)
// ============================================================
__global__ __launch_bounds__(256)
void merge_factors_kernel(const float* __restrict__ mh0, const float* __restrict__ mh1,
                          const float* __restrict__ lh0, const float* __restrict__ lh1,
                          float* __restrict__ g0, float* __restrict__ g1)
{
    const int row = blockIdx.x * 256 + threadIdx.x;   // 32768 rows
    float m0 = mh0[row], m1 = mh1[row];
    float m  = fmaxf(m0, m1);
    float e0 = __expf(m0 - m), e1 = __expf(m1 - m);
    float inv = 1.0f / (lh0[row]*e0 + lh1[row]*e1);
    g0[row] = e0 * inv;
    g1[row] = e1 * inv;
}

// ============================================================
// attention[row][col] *= g_{col/1024}[row]
// ============================================================
__global__ __launch_bounds__(256)
void scale_attn_kernel(float* __restrict__ attnbuf,
                       const float* __restrict__ g0, const float* __restrict__ g1)
{
    const size_t idx = (size_t)blockIdx.x * 256 + threadIdx.x;  // float4 index
    const size_t g   = idx * 4;
    const size_t row = g >> 11;
    const u32    col = (u32)(g & 2047);
    const float fac = (col >= 1024 ? g1 : g0)[row];
    float4* p = (float4*)attnbuf + idx;
    float4 v = *p;
    v.x *= fac; v.y *= fac; v.z *= fac; v.w *= fac;
    *p = v;
}

// ============================================================
// O projection with in-staging merge: a = pO0*g0 + pO1*g1, then
// split-bf16 3-term MFMA with Wo. out = a @ Wo^T + bo.
// ============================================================
__global__ __launch_bounds__(256, 2)
void oproj_mfma_kernel(const u16* __restrict__ pA0, const u16* __restrict__ pA1,
                       const float* __restrict__ g0, const float* __restrict__ g1,
                       const float* __restrict__ Wo, const float* __restrict__ bo,
                       float* __restrict__ out, int z)
{
    float* outp = out + (size_t)z * PE_;

    const int m0 = blockIdx.x * 128;
    const int n0 = blockIdx.y * 64;

    __shared__ __align__(16) unsigned char L[49152];
    enum : u32 { AH=0, AL=16384, BH=32768, BL=40960 };

    const int tid  = threadIdx.x;
    const int lane = tid & 63;
    const int wid  = tid >> 6;
    const int wr   = wid >> 1, wc = wid & 1;
    const int l31  = lane & 31;
    const int hi   = lane >> 5;
    const u32 rowA0 = (u32)(wr*64 + l31);
    const u32 rowB  = (u32)(wc*32 + l31);

    f32x16 c0, c1;
    #pragma unroll
    for (int r = 0; r < 16; ++r) { c0[r] = 0.f; c1[r] = 0.f; }

    const int ch = tid & 7, r0 = tid >> 3;

    for (int k0 = 0; k0 < 512; k0 += 64) {
        const int head = (k0 + ch*8) >> 6;
        __syncthreads();
        #pragma unroll
        for (int rr = 0; rr < 4; ++rr) {
            u32 row = (u32)(rr*32 + r0);
            int gm = m0 + row;
            int b_ = gm >> 11, i = gm & 2047;
            size_t gidx = (size_t)(b_*8 + head)*2048 + i;
            float gg0 = g0[gidx], gg1 = g1[gidx];
            us8 p0 = *(const us8*)(pA0 + (size_t)gm*512 + k0 + ch*8);
            us8 p1 = *(const us8*)(pA1 + (size_t)gm*512 + k0 + ch*8);
            us8 hv, lv;
            #pragma unroll
            for (int j = 0; j < 8; ++j) {
                float a = bf2f(p0[j])*gg0 + bf2f(p1[j])*gg1;
                u16 hb = f2bf(a);
                hv[j] = hb;
                lv[j] = f2bf(a - bf2f(hb));
            }
            u32 dst = row*128u + (((u32)ch<<4) ^ ((row&7u)<<4));
            *(us8*)(L + AH + dst) = hv;
            *(us8*)(L + AL + dst) = lv;
        }
        #pragma unroll
        for (int rr = 0; rr < 2; ++rr) {
            u32 row = (u32)(rr*32 + r0);
            const float* src = Wo + (size_t)(n0 + row)*512 + k0 + ch*8;
            float4 v0 = *(const float4*)src;
            float4 v1 = *(const float4*)(src + 4);
            float vv[8] = { v0.x,v0.y,v0.z,v0.w, v1.x,v1.y,v1.z,v1.w };
            us8 hv, lv;
            #pragma unroll
            for (int j = 0; j < 8; ++j) {
                u16 hb = f2bf(vv[j]);
                hv[j] = hb;
                lv[j] = f2bf(vv[j] - bf2f(hb));
            }
            u32 dst = row*128u + (((u32)ch<<4) ^ ((row&7u)<<4));
            *(us8*)(L + BH + dst) = hv;
            *(us8*)(L + BL + dst) = lv;
        }
        __syncthreads();

        #pragma unroll
        for (int ks = 0; ks < 4; ++ks) {
            u32 colb = (u32)(ks*32 + hi*16);
            s8v a0h = ldfrag(L, AH, rowA0,      colb);
            s8v a1h = ldfrag(L, AH, rowA0 + 32, colb);
            s8v a0l = ldfrag(L, AL, rowA0,      colb);
            s8v a1l = ldfrag(L, AL, rowA0 + 32, colb);
            s8v bh_ = ldfrag(L, BH, rowB,       colb);
            s8v bl_ = ldfrag(L, BL, rowB,       colb);
            c0 = MFMA32(a0h, bh_, c0); c0 = MFMA32(a0h, bl_, c0); c0 = MFMA32(a0l, bh_, c0);
            c1 = MFMA32(a1h, bh_, c1); c1 = MFMA32(a1h, bl_, c1); c1 = MFMA32(a1l, bh_, c1);
        }
    }

    const int n = n0 + wc*32 + l31;
    const float bvv = bo[n];
    #pragma unroll
    for (int f = 0; f < 2; ++f) {
        const f32x16& c = f ? c1 : c0;
        #pragma unroll
        for (int r = 0; r < 16; ++r) {
            int m = m0 + wr*64 + 32*f + ROWOF(r, hi);
            outp[(size_t)m*512 + n] = c[r] + bvv;
        }
    }
}

// ============================================================
extern "C" void kernel_launch(void* const* d_in, const int* in_sizes, int n_in,
                              void* d_out, int out_size, void* d_ws, size_t ws_size,
                              hipStream_t stream)
{
    const float* wave_real = (const float*)d_in[0];
    const float* wave_imag = (const float*)d_in[1];
    const float* Wq = (const float*)d_in[2]; const float* bq = (const float*)d_in[3];
    const float* Wk = (const float*)d_in[4]; const float* bk = (const float*)d_in[5];
    const float* Wv = (const float*)d_in[6]; const float* bv = (const float*)d_in[7];
    const float* Wo = (const float*)d_in[8]; const float* bo = (const float*)d_in[9];
    float* out = (float*)d_out;
    unsigned char* outb = (unsigned char*)d_out;
    unsigned char* wsb  = (unsigned char*)d_ws;

    float* attnbuf = out + 2*PE_;

    split_prep_kernel<<<dim3(2048, 2), dim3(256), 0, stream>>>(wave_real, wave_imag, outb);

    proj_mfma_kernel<<<dim3(32, 8, 6), dim3(256), 0, stream>>>(
        outb, Wq, Wk, Wv, bq, bk, bv,
        (u16*)wsb, (u16*)(wsb + VT_OFF));

    attn_mfma_kernel<<<dim3(16, 32, 2), dim3(256), 0, stream>>>(
        (const u16*)wsb, (const u16*)(wsb + VT_OFF), attnbuf,
        (u16*)(wsb + POR0_OFF), (u16*)(wsb + POR1_OFF),
        (u16*)(wsb + POI0_OFF), (u16*)(wsb + POI1_OFF),
        (float*)(wsb + MH0_OFF), (float*)(wsb + MH1_OFF),
        (float*)(wsb + LH0_OFF), (float*)(wsb + LH1_OFF));

    merge_factors_kernel<<<dim3(128), dim3(256), 0, stream>>>(
        (const float*)(wsb + MH0_OFF), (const float*)(wsb + MH1_OFF),
        (const float*)(wsb + LH0_OFF), (const float*)(wsb + LH1_OFF),
        (float*)(wsb + G0_OFF), (float*)(wsb + G1_OFF));

    scale_attn_kernel<<<dim3(65536), dim3(256), 0, stream>>>(
        attnbuf, (const float*)(wsb + G0_OFF), (const float*)(wsb + G1_OFF));

    oproj_mfma_kernel<<<dim3(32, 8), dim3(256), 0, stream>>>(
        (const u16*)(wsb + POR0_OFF), (const u16*)(wsb + POR1_OFF),
        (const float*)(wsb + G0_OFF), (const float*)(wsb + G1_OFF),
        Wo, bo, out, 0);
    oproj_mfma_kernel<<<dim3(32, 8), dim3(256), 0, stream>>>(
        (const u16*)(wsb + POI0_OFF), (const u16*)(wsb + POI1_OFF),
        (const float*)(wsb + G0_OFF), (const float*)(wsb + G1_OFF),
        Wo, bo, out, 1);
}

// Round 9
// 444.062 us; speedup vs baseline: 1.7402x; 1.7402x over previous
//
#include <hip/hip_runtime.h>

typedef unsigned short u16;
typedef unsigned int   u32;
typedef __attribute__((ext_vector_type(4)))  u16   us4;
typedef __attribute__((ext_vector_type(8)))  u16   us8;
typedef __attribute__((ext_vector_type(8)))  short s8v;
typedef __attribute__((ext_vector_type(16))) float f32x16;

#define L_   2048
#define D_   512
#define H_   8
#define PE_  2097152ull      // B*L*D elements of one fp32 projection array

// ---- ws layout (bytes) ----
//  [0 .. 32MB)   : 8 bf16 mats (QRH,QRL,QIH,QIL,KRH,KRL,KIH,KIL), each [bh][i][64]
//  [32 .. 40MB)  : 2 bf16 mats VTR,VTI, each [bh][dh][2048]  (V transposed)
//  [40 .. 56MB)  : o splits: ORH,ORL,OIH,OIL bf16 [4096][512]
//  [56MB ..]     : l (32768 fp32)
#define MATE    2097152ull   // u16 elems per mat
#define BHE     131072u      // u16 elems per (bh) slice of a mat (2048*64)
#define VT_OFF  33554432ull
#define ORH_OFF 41943040ull
#define ORL_OFF 46137344ull
#define OIH_OFF 50331648ull
#define OIL_OFF 54525952ull
#define LV_OFF  58720256ull

// ---- d_out scratch (bytes from out base; inside attnbuf, dead before attn writes) ----
#define XRH_O 16777216ull
#define XRL_O 20971520ull
#define XIH_O 25165824ull
#define XIL_O 29360128ull

#define MFMA32(a,b,c) __builtin_amdgcn_mfma_f32_32x32x16_bf16(a,b,c,0,0,0)
#define ROWOF(r,hi) (((r)&3) + 8*((r)>>2) + 4*(hi))

__device__ __forceinline__ u16 f2bf(float x){
    u32 u = __float_as_uint(x);
    u += 0x7FFFu + ((u>>16)&1u);
    return (u16)(u>>16);
}
__device__ __forceinline__ float bf2f(u16 h){ return __uint_as_float(((u32)h)<<16); }

// ============================================================
// Prep: split wave_real / wave_imag into bf16 hi/lo mats (d_out scratch)
// ============================================================
__global__ __launch_bounds__(256)
void split_prep_kernel(const float* __restrict__ wr, const float* __restrict__ wi,
                       unsigned char* __restrict__ outb)
{
    const int z = blockIdx.y;
    const float* src = z ? wi : wr;
    u16* hg = (u16*)(outb + (z ? XIH_O : XRH_O));
    u16* lg = (u16*)(outb + (z ? XIL_O : XRL_O));
    const size_t idx4 = ((size_t)blockIdx.x * 256 + threadIdx.x) * 4;
    float4 v = *(const float4*)&src[idx4];
    float vv[4] = { v.x, v.y, v.z, v.w };
    us4 h, l;
    #pragma unroll
    for (int c = 0; c < 4; ++c) {
        u16 hb = f2bf(vv[c]);
        h[c] = hb;
        l[c] = f2bf(vv[c] - bf2f(hb));
    }
    *(us4*)&hg[idx4] = h;
    *(us4*)&lg[idx4] = l;
}

// ============================================================
// LDS helpers (XOR swizzle byte ^= (row&7)<<4, both sides)
// ============================================================
__device__ __forceinline__ s8v ldfrag(const unsigned char* Lp, u32 matOff, u32 row, u32 colb)
{
    return *(const s8v*)(Lp + matOff + row*128u + (colb ^ ((row&7u)<<4)));
}
__device__ __forceinline__ void stage_qk(unsigned char* Lp, u32 matOff,
                                         const u16* __restrict__ g, int rowBase, int tid)
{
    const int ch = tid & 7;
    const int r0 = tid >> 3;
    #pragma unroll
    for (int rr = 0; rr < 2; ++rr) {
        u32 row = rr*32 + r0;
        us8 v = ((const us8*)(g + (size_t)(rowBase + row)*64))[ch];
        *(us8*)(Lp + matOff + row*128u + (((u32)ch<<4) ^ ((row&7u)<<4))) = v;
    }
}
__device__ __forceinline__ void stage_vt(unsigned char* Lp, u32 matOff,
                                         const u16* __restrict__ g, int j0, int tid, bool neg)
{
    const int ch = tid & 7;
    const int r0 = tid >> 3;
    #pragma unroll
    for (int rr = 0; rr < 2; ++rr) {
        u32 dh = rr*32 + r0;
        us8 v = ((const us8*)(g + (size_t)dh*2048 + j0))[ch];
        if (neg) v = v ^ (u16)0x8000u;
        *(us8*)(Lp + matOff + dh*128u + (((u32)ch<<4) ^ ((dh&7u)<<4))) = v;
    }
}

// reg-staged 64x64 bf16 mat (sweep-1 K prefetch only)
struct regs2 { us8 a, b; };
__device__ __forceinline__ void load_mat_qk(regs2& r, const u16* __restrict__ g,
                                            int rowBase, int ch, int r0)
{
    r.a = *(const us8*)(g + (size_t)(rowBase + r0)*64 + ch*8);
    r.b = *(const us8*)(g + (size_t)(rowBase + 32 + r0)*64 + ch*8);
}
__device__ __forceinline__ void write_mat(unsigned char* Lp, u32 off, const regs2& r,
                                          int ch, int r0)
{
    u32 row0 = (u32)r0, row1 = (u32)(32 + r0);
    *(us8*)(Lp + off + row0*128u + (((u32)ch<<4) ^ ((row0&7u)<<4))) = r.a;
    *(us8*)(Lp + off + row1*128u + (((u32)ch<<4) ^ ((row1&7u)<<4))) = r.b;
}

// ============================================================
// MFMA projection: C = X @ W^T + b for 6 combos. (unchanged, proven)
// ============================================================
__global__ __launch_bounds__(256, 2)
void proj_mfma_kernel(const unsigned char* __restrict__ scr,
                      const float* __restrict__ Wq, const float* __restrict__ Wk,
                      const float* __restrict__ Wv,
                      const float* __restrict__ bq, const float* __restrict__ bk,
                      const float* __restrict__ bv,
                      u16* __restrict__ qk, u16* __restrict__ vt)
{
    const int z = blockIdx.z;
    const u16* Ah_g = (const u16*)(scr + ((z & 1) ? XIH_O : XRH_O));
    const u16* Al_g = (const u16*)(scr + ((z & 1) ? XIL_O : XRL_O));
    const int wsel = z >> 1;
    const float* Wf; const float* bias;
    if (wsel == 0)      { Wf = Wq; bias = bq; }
    else if (wsel == 1) { Wf = Wk; bias = bk; }
    else                { Wf = Wv; bias = bv; }
    const bool four = (wsel < 2);

    const int m0 = blockIdx.x * 128;
    const int n0 = blockIdx.y * 64;

    __shared__ __align__(16) unsigned char L[49152];
    enum : u32 { AH=0, AL=16384, BH=32768, BL=40960 };

    const int tid  = threadIdx.x;
    const int lane = tid & 63;
    const int wid  = tid >> 6;
    const int wr   = wid >> 1, wc = wid & 1;
    const int l31  = lane & 31;
    const int hi   = lane >> 5;
    const u32 rowA0 = (u32)(wr*64 + l31);
    const u32 rowB  = (u32)(wc*32 + l31);

    f32x16 c0, c1;
    #pragma unroll
    for (int r = 0; r < 16; ++r) { c0[r] = 0.f; c1[r] = 0.f; }

    const int ch = tid & 7, r0 = tid >> 3;

    for (int k0 = 0; k0 < 512; k0 += 64) {
        __syncthreads();
        #pragma unroll
        for (int rr = 0; rr < 4; ++rr) {
            u32 row = (u32)(rr*32 + r0);
            u32 dst = row*128u + (((u32)ch<<4) ^ ((row&7u)<<4));
            us8 vh = *(const us8*)(Ah_g + (size_t)(m0 + row)*512 + k0 + ch*8);
            *(us8*)(L + AH + dst) = vh;
            if (four) {
                us8 vl = *(const us8*)(Al_g + (size_t)(m0 + row)*512 + k0 + ch*8);
                *(us8*)(L + AL + dst) = vl;
            }
        }
        #pragma unroll
        for (int rr = 0; rr < 2; ++rr) {
            u32 row = (u32)(rr*32 + r0);
            const float* src = Wf + (size_t)(n0 + row)*512 + k0 + ch*8;
            float4 v0 = *(const float4*)src;
            float4 v1 = *(const float4*)(src + 4);
            float vv[8] = { v0.x,v0.y,v0.z,v0.w, v1.x,v1.y,v1.z,v1.w };
            us8 hv, lv;
            #pragma unroll
            for (int j = 0; j < 8; ++j) {
                u16 hb = f2bf(vv[j]);
                hv[j] = hb;
                lv[j] = f2bf(vv[j] - bf2f(hb));
            }
            u32 dst = row*128u + (((u32)ch<<4) ^ ((row&7u)<<4));
            *(us8*)(L + BH + dst) = hv;
            if (four) *(us8*)(L + BL + dst) = lv;
        }
        __syncthreads();

        #pragma unroll
        for (int ks = 0; ks < 4; ++ks) {
            u32 colb = (u32)(ks*32 + hi*16);
            s8v a0h = ldfrag(L, AH, rowA0,      colb);
            s8v a1h = ldfrag(L, AH, rowA0 + 32, colb);
            s8v bh_ = ldfrag(L, BH, rowB,       colb);
            c0 = MFMA32(a0h, bh_, c0);
            c1 = MFMA32(a1h, bh_, c1);
            if (four) {
                s8v a0l = ldfrag(L, AL, rowA0,      colb);
                s8v a1l = ldfrag(L, AL, rowA0 + 32, colb);
                s8v bl_ = ldfrag(L, BL, rowB,       colb);
                c0 = MFMA32(a0h, bl_, c0); c0 = MFMA32(a0l, bh_, c0); c0 = MFMA32(a0l, bl_, c0);
                c1 = MFMA32(a1h, bl_, c1); c1 = MFMA32(a1l, bh_, c1); c1 = MFMA32(a1l, bl_, c1);
            }
        }
    }

    const int n  = n0 + wc*32 + l31;
    const float bvv = bias[n];
    const int h  = n >> 6, dh = n & 63;

    if (z < 4) {
        u16* hg = qk + (size_t)(2*z)   * MATE;
        u16* lg = qk + (size_t)(2*z+1) * MATE;
        #pragma unroll
        for (int f = 0; f < 2; ++f) {
            const f32x16& c = f ? c1 : c0;
            #pragma unroll
            for (int r = 0; r < 16; ++r) {
                int m  = m0 + wr*64 + 32*f + ROWOF(r, hi);
                int b_ = m >> 11, i = m & 2047;
                size_t idx = (size_t)(b_*8 + h)*BHE + (size_t)i*64 + dh;
                float v = c[r] + bvv;
                u16 hb = f2bf(v);
                hg[idx] = hb;
                lg[idx] = f2bf(v - bf2f(hb));
            }
        }
    } else {
        u16* vg = vt + (size_t)(z & 1) * MATE;
        #pragma unroll
        for (int f = 0; f < 2; ++f) {
            const f32x16& c = f ? c1 : c0;
            #pragma unroll
            for (int g = 0; g < 4; ++g) {
                int mb = m0 + wr*64 + 32*f + 8*g + 4*hi;
                int b_ = mb >> 11, ib = mb & 2047;
                us4 pv;
                #pragma unroll
                for (int j = 0; j < 4; ++j) pv[j] = f2bf(c[4*g + j] + bvv);
                *(us4*)&vg[(size_t)(b_*8 + h)*BHE + (size_t)dh*2048 + ib] = pv;
            }
        }
    }
}

// ============================================================
// MFMA attention — R3 two-sweep structure + proven-safe deltas:
//  * qf in registers (R6-safe), 2-acc QK via sign-flipped A (R8 math)
//  * sweep1: LDS dbuf K + 2-deep reg prefetch, 1 barrier/jt (R6-safe)
//  * sweep2: R3's exact 4-barrier skeleton (V staged after QK, hidden
//    under pointwise); NO reg prefetch (R7 spill lesson)
//  * XCD chunk swizzle: each XCD owns 2 bh values (K/V 3MB < 4MB L2)
// LDS 48.5 KB.
// ============================================================
__global__ __launch_bounds__(256, 2)
void attn_mfma_kernel(const u16* __restrict__ qk,
                      const u16* __restrict__ vt,
                      float* __restrict__ attnbuf,
                      u16* __restrict__ orh, u16* __restrict__ orl,
                      u16* __restrict__ oih, u16* __restrict__ oil,
                      float* __restrict__ l_out)
{
    const int bid = blockIdx.x;
    const int swz = (bid & 7) * 64 + (bid >> 3);   // XCD chunk: 64 blocks = 2 bh per XCD
    const int bh  = swz >> 5;
    const int i0  = (swz & 31) * 64;
    const int tid  = threadIdx.x;
    const int lane = tid & 63;
    const int wid  = tid >> 6;
    const int wr   = wid >> 1, wc = wid & 1;
    const int l31  = lane & 31;
    const int hi   = lane >> 5;
    const u32 rowA = wr*32 + l31;
    const u32 rowB = wc*32 + l31;
    const int ch = tid & 7, r0 = tid >> 3;

    __shared__ __align__(16) unsigned char L[49152];
    __shared__ float xsc[128];
    enum : u32 { KRH=0, KRL=8192, KIH=16384, KIL=24576,
                 S1A=0, S1B=16384,
                 VRo=0, VIo=8192, VNo=16384,
                 PAC=32768, PAS=40960 };

    const u16* qrh = qk + 0*MATE + (size_t)bh*BHE;
    const u16* qrl = qk + 1*MATE + (size_t)bh*BHE;
    const u16* qih = qk + 2*MATE + (size_t)bh*BHE;
    const u16* qil = qk + 3*MATE + (size_t)bh*BHE;
    const u16* krh = qk + 4*MATE + (size_t)bh*BHE;
    const u16* krl = qk + 5*MATE + (size_t)bh*BHE;
    const u16* kih = qk + 6*MATE + (size_t)bh*BHE;
    const u16* kil = qk + 7*MATE + (size_t)bh*BHE;
    const u16* vtr = vt + 0*MATE + (size_t)bh*BHE;
    const u16* vti = vt + 1*MATE + (size_t)bh*BHE;

    // ---- prologue: K(0) hi loads; Q -> LDS {PAC,PAS,KIH,KIL}; K(0) -> S1A ----
    regs2 s1k[2];
    load_mat_qk(s1k[0], krh, 0, ch, r0);
    load_mat_qk(s1k[1], kih, 0, ch, r0);
    stage_qk(L, PAC, qrh, i0, tid);
    stage_qk(L, PAS, qrl, i0, tid);
    stage_qk(L, KIH, qih, i0, tid);
    stage_qk(L, KIL, qil, i0, tid);
    write_mat(L, S1A + 0,    s1k[0], ch, r0);
    write_mat(L, S1A + 8192, s1k[1], ch, r0);
    __syncthreads();

    // Q fragments -> registers (64 VGPR)
    s8v qf[4][4];
    #pragma unroll
    for (int ks = 0; ks < 4; ++ks) {
        u32 colb = (u32)(ks*32 + hi*16);
        qf[0][ks] = ldfrag(L, PAC, rowA, colb);
        qf[1][ks] = ldfrag(L, PAS, rowA, colb);
        qf[2][ks] = ldfrag(L, KIH, rowA, colb);
        qf[3][ks] = ldfrag(L, KIL, rowA, colb);
    }
    load_mat_qk(s1k[0], krh, 64, ch, r0);    // prefetch K(1)
    load_mat_qk(s1k[1], kih, 64, ch, r0);

    // ---------------- sweep 1: approx row max (hi*hi), dbuf, 1 barrier/jt ----------------
    float mx[16];
    #pragma unroll
    for (int r = 0; r < 16; ++r) mx[r] = 0.f;

    u32 cur = S1A, nxt = S1B;
    for (int jt = 0; jt < 32; ++jt) {
        __syncthreads();                       // K(jt) visible; nxt free (also fences qf lift at jt=0)
        f32x16 ir, ii;
        #pragma unroll
        for (int r = 0; r < 16; ++r) { ir[r]=0.f; ii[r]=0.f; }
        __builtin_amdgcn_s_setprio(1);
        #pragma unroll
        for (int ks = 0; ks < 4; ++ks) {
            u32 colb = (u32)(ks*32 + hi*16);
            s8v bR = ldfrag(L, cur + 0,    rowB, colb);
            s8v bI = ldfrag(L, cur + 8192, rowB, colb);
            s8v nq2 = qf[2][ks] ^ (short)0x8000;
            ir = MFMA32(qf[0][ks], bR, ir);
            ir = MFMA32(qf[2][ks], bI, ir);
            ii = MFMA32(qf[0][ks], bI, ii);
            ii = MFMA32(nq2,       bR, ii);
        }
        __builtin_amdgcn_s_setprio(0);
        if (jt < 31) {
            write_mat(L, nxt + 0,    s1k[0], ch, r0);
            write_mat(L, nxt + 8192, s1k[1], ch, r0);
        }
        if (jt < 30) {
            load_mat_qk(s1k[0], krh, (jt+2)*64, ch, r0);
            load_mat_qk(s1k[1], kih, (jt+2)*64, ch, r0);
        }
        #pragma unroll
        for (int r = 0; r < 16; ++r)
            mx[r] = fmaxf(mx[r], fmaf(ir[r], ir[r], ii[r]*ii[r]) * 0.125f);
        u32 t = cur; cur = nxt; nxt = t;
    }
    #pragma unroll
    for (int m = 1; m < 32; m <<= 1)
        #pragma unroll
        for (int r = 0; r < 16; ++r) mx[r] = fmaxf(mx[r], __shfl_xor(mx[r], m));

    __syncthreads();                           // last sweep1 reads done
    if (l31 == 0) {
        #pragma unroll
        for (int r = 0; r < 16; ++r)
            xsc[(wr*32 + ROWOF(r,hi))*2 + wc] = mx[r];
    }
    __syncthreads();
    float mfin[16];
    #pragma unroll
    for (int r = 0; r < 16; ++r) {
        u32 row = wr*32 + ROWOF(r,hi);
        mfin[r] = fmaxf(xsc[row*2], xsc[row*2 + 1]);
    }

    // ---------------- sweep 2 (R3's exact 4-barrier skeleton) ----------------
    f32x16 ore, oim;
    float lp[16];
    #pragma unroll
    for (int r = 0; r < 16; ++r) { ore[r]=0.f; oim[r]=0.f; lp[r]=0.f; }

    for (int jt = 0; jt < 32; ++jt) {
        const int j0 = jt * 64;
        __syncthreads();                       // #1: prev PV done -> K/V regions free
        stage_qk(L, KRH, krh, j0, tid);
        stage_qk(L, KRL, krl, j0, tid);
        stage_qk(L, KIH, kih, j0, tid);
        stage_qk(L, KIL, kil, j0, tid);
        __syncthreads();                       // #2: K staged

        f32x16 ir, ii;
        #pragma unroll
        for (int r = 0; r < 16; ++r) { ir[r]=0.f; ii[r]=0.f; }
        __builtin_amdgcn_s_setprio(1);
        #pragma unroll
        for (int ks = 0; ks < 4; ++ks) {
            u32 colb = (u32)(ks*32 + hi*16);
            s8v bRH = ldfrag(L, KRH, rowB, colb);
            s8v bRL = ldfrag(L, KRL, rowB, colb);
            s8v bIH = ldfrag(L, KIH, rowB, colb);
            s8v bIL = ldfrag(L, KIL, rowB, colb);
            s8v nq2 = qf[2][ks] ^ (short)0x8000;
            s8v nq3 = qf[3][ks] ^ (short)0x8000;
            ir = MFMA32(qf[0][ks], bRH, ir); ir = MFMA32(qf[0][ks], bRL, ir); ir = MFMA32(qf[1][ks], bRH, ir);
            ir = MFMA32(qf[2][ks], bIH, ir); ir = MFMA32(qf[2][ks], bIL, ir); ir = MFMA32(qf[3][ks], bIH, ir);
            ii = MFMA32(qf[0][ks], bIH, ii); ii = MFMA32(qf[0][ks], bIL, ii); ii = MFMA32(qf[1][ks], bIH, ii);
            ii = MFMA32(nq2,       bRH, ii); ii = MFMA32(nq2,       bRL, ii); ii = MFMA32(nq3,       bRH, ii);
        }
        __builtin_amdgcn_s_setprio(0);
        __syncthreads();                       // #3: K reads done -> V may overwrite

        stage_vt(L, VRo, vtr, j0, tid, false);
        stage_vt(L, VIo, vti, j0, tid, false);
        stage_vt(L, VNo, vti, j0, tid, true);  // -Vi

        // pointwise (hides the V loads): unnormalized e -> attnbuf; P -> LDS
        float* arow = attnbuf + (size_t)bh*4194304ull + (size_t)i0*2048 + j0 + wc*32 + l31;
        #pragma unroll
        for (int r = 0; r < 16; ++r) {
            float xr = ir[r], xi = ii[r];
            float q  = fmaf(xr, xr, xi*xi);
            float e  = __expf(fmaf(q, 0.125f, -mfin[r]));
            lp[r] += e;
            float iv = rsqrtf(fmaxf(q, 1e-37f));
            float cc = xr * iv;
            float ss = xi * iv;
            u32 rowloc = wr*32 + ROWOF(r,hi);
            arow[(size_t)rowloc*2048] = e;
            u32 colb2 = (wc*32 + l31)*2;
            *(u16*)(L + PAC + rowloc*128u + (colb2 ^ ((rowloc&7u)<<4))) = f2bf(e*cc);
            *(u16*)(L + PAS + rowloc*128u + (colb2 ^ ((rowloc&7u)<<4))) = f2bf(e*ss);
        }
        __syncthreads();                       // #4: V,P visible

        __builtin_amdgcn_s_setprio(1);
        #pragma unroll
        for (int ks = 0; ks < 4; ++ks) {
            u32 colb = (u32)(ks*32 + hi*16);
            s8v aC = ldfrag(L, PAC, rowA, colb);
            s8v aS = ldfrag(L, PAS, rowA, colb);
            s8v vR = ldfrag(L, VRo, rowB, colb);
            s8v vI = ldfrag(L, VIo, rowB, colb);
            s8v vN = ldfrag(L, VNo, rowB, colb);
            ore = MFMA32(aC, vR, ore); ore = MFMA32(aS, vN, ore);
            oim = MFMA32(aS, vR, oim); oim = MFMA32(aC, vI, oim);
        }
        __builtin_amdgcn_s_setprio(0);
    }

    // ---------------- epilogue: l, normalize O, store ----------------
    #pragma unroll
    for (int m = 1; m < 32; m <<= 1)
        #pragma unroll
        for (int r = 0; r < 16; ++r) lp[r] += __shfl_xor(lp[r], m);

    __syncthreads();                           // last PV done; xsc free
    if (l31 == 0) {
        #pragma unroll
        for (int r = 0; r < 16; ++r)
            xsc[(wr*32 + ROWOF(r,hi))*2 + wc] = lp[r];
    }
    __syncthreads();

    const int b_ = bh >> 3, h = bh & 7;
    const size_t cb = (size_t)h*64 + wc*32 + l31;
    #pragma unroll
    for (int r = 0; r < 16; ++r) {
        u32 row = wr*32 + ROWOF(r,hi);
        float ls = xsc[row*2] + xsc[row*2 + 1];
        if (wc == 0 && l31 == 0) l_out[(size_t)bh*2048 + i0 + row] = ls;
        float inv = 1.0f / ls;
        size_t idx = ((size_t)b_*2048 + i0 + row)*512 + cb;
        float vr = ore[r] * inv;
        float vi = oim[r] * inv;
        u16 hr = f2bf(vr); orh[idx] = hr; orl[idx] = f2bf(vr - bf2f(hr));
        u16 hw = f2bf(vi); oih[idx] = hw; oil[idx] = f2bf(vi - bf2f(hw));
    }
}

// ============================================================
// attention *= 1/l[row]
// ============================================================
__global__ __launch_bounds__(256)
void scale_attn_kernel(float* __restrict__ attnbuf, const float* __restrict__ l)
{
    const size_t idx = (size_t)blockIdx.x * 256 + threadIdx.x;
    const size_t row = idx >> 9;
    const float inv = 1.f / l[row];
    float4* p = (float4*)attnbuf + idx;
    float4 v = *p;
    v.x *= inv; v.y *= inv; v.z *= inv; v.w *= inv;
    *p = v;
}

// ============================================================
// O projection: out = o @ Wo^T + bo, 3-term split-bf16 MFMA. (unchanged)
// ============================================================
__global__ __launch_bounds__(256, 2)
void oproj_mfma_kernel(const unsigned char* __restrict__ wsb,
                       const float* __restrict__ Wo, const float* __restrict__ bo,
                       float* __restrict__ out)
{
    const int z = blockIdx.z;
    const u16* Ah_g = (const u16*)(wsb + (z ? OIH_OFF : ORH_OFF));
    const u16* Al_g = (const u16*)(wsb + (z ? OIL_OFF : ORL_OFF));
    float* outp = out + (size_t)z * PE_;

    const int m0 = blockIdx.x * 128;
    const int n0 = blockIdx.y * 64;

    __shared__ __align__(16) unsigned char L[49152];
    enum : u32 { AH=0, AL=16384, BH=32768, BL=40960 };

    const int tid  = threadIdx.x;
    const int lane = tid & 63;
    const int wid  = tid >> 6;
    const int wr   = wid >> 1, wc = wid & 1;
    const int l31  = lane & 31;
    const int hi   = lane >> 5;
    const u32 rowA0 = (u32)(wr*64 + l31);
    const u32 rowB  = (u32)(wc*32 + l31);

    f32x16 c0, c1;
    #pragma unroll
    for (int r = 0; r < 16; ++r) { c0[r] = 0.f; c1[r] = 0.f; }

    const int ch = tid & 7, r0 = tid >> 3;

    for (int k0 = 0; k0 < 512; k0 += 64) {
        __syncthreads();
        #pragma unroll
        for (int rr = 0; rr < 4; ++rr) {
            u32 row = (u32)(rr*32 + r0);
            u32 dst = row*128u + (((u32)ch<<4) ^ ((row&7u)<<4));
            us8 vh = *(const us8*)(Ah_g + (size_t)(m0 + row)*512 + k0 + ch*8);
            us8 vl = *(const us8*)(Al_g + (size_t)(m0 + row)*512 + k0 + ch*8);
            *(us8*)(L + AH + dst) = vh;
            *(us8*)(L + AL + dst) = vl;
        }
        #pragma unroll
        for (int rr = 0; rr < 2; ++rr) {
            u32 row = (u32)(rr*32 + r0);
            const float* src = Wo + (size_t)(n0 + row)*512 + k0 + ch*8;
            float4 v0 = *(const float4*)src;
            float4 v1 = *(const float4*)(src + 4);
            float vv[8] = { v0.x,v0.y,v0.z,v0.w, v1.x,v1.y,v1.z,v1.w };
            us8 hv, lv;
            #pragma unroll
            for (int j = 0; j < 8; ++j) {
                u16 hb = f2bf(vv[j]);
                hv[j] = hb;
                lv[j] = f2bf(vv[j] - bf2f(hb));
            }
            u32 dst = row*128u + (((u32)ch<<4) ^ ((row&7u)<<4));
            *(us8*)(L + BH + dst) = hv;
            *(us8*)(L + BL + dst) = lv;
        }
        __syncthreads();

        #pragma unroll
        for (int ks = 0; ks < 4; ++ks) {
            u32 colb = (u32)(ks*32 + hi*16);
            s8v a0h = ldfrag(L, AH, rowA0,      colb);
            s8v a1h = ldfrag(L, AH, rowA0 + 32, colb);
            s8v a0l = ldfrag(L, AL, rowA0,      colb);
            s8v a1l = ldfrag(L, AL, rowA0 + 32, colb);
            s8v bh_ = ldfrag(L, BH, rowB,       colb);
            s8v bl_ = ldfrag(L, BL, rowB,       colb);
            c0 = MFMA32(a0h, bh_, c0); c0 = MFMA32(a0h, bl_, c0); c0 = MFMA32(a0l, bh_, c0);
            c1 = MFMA32(a1h, bh_, c1); c1 = MFMA32(a1h, bl_, c1); c1 = MFMA32(a1l, bh_, c1);
        }
    }

    const int n = n0 + wc*32 + l31;
    const float bvv = bo[n];
    #pragma unroll
    for (int f = 0; f < 2; ++f) {
        const f32x16& c = f ? c1 : c0;
        #pragma unroll
        for (int r = 0; r < 16; ++r) {
            int m = m0 + wr*64 + 32*f + ROWOF(r, hi);
            outp[(size_t)m*512 + n] = c[r] + bvv;
        }
    }
}

// ============================================================
extern "C" void kernel_launch(void* const* d_in, const int* in_sizes, int n_in,
                              void* d_out, int out_size, void* d_ws, size_t ws_size,
                              hipStream_t stream)
{
    const float* wave_real = (const float*)d_in[0];
    const float* wave_imag = (const float*)d_in[1];
    const float* Wq = (const float*)d_in[2]; const float* bq = (const float*)d_in[3];
    const float* Wk = (const float*)d_in[4]; const float* bk = (const float*)d_in[5];
    const float* Wv = (const float*)d_in[6]; const float* bv = (const float*)d_in[7];
    const float* Wo = (const float*)d_in[8]; const float* bo = (const float*)d_in[9];
    float* out = (float*)d_out;
    unsigned char* outb = (unsigned char*)d_out;
    unsigned char* wsb  = (unsigned char*)d_ws;

    float* attnbuf = out + 2*PE_;

    split_prep_kernel<<<dim3(2048, 2), dim3(256), 0, stream>>>(wave_real, wave_imag, outb);

    proj_mfma_kernel<<<dim3(32, 8, 6), dim3(256), 0, stream>>>(
        outb, Wq, Wk, Wv, bq, bk, bv,
        (u16*)wsb, (u16*)(wsb + VT_OFF));

    attn_mfma_kernel<<<dim3(512), dim3(256), 0, stream>>>(
        (const u16*)wsb, (const u16*)(wsb + VT_OFF), attnbuf,
        (u16*)(wsb + ORH_OFF), (u16*)(wsb + ORL_OFF),
        (u16*)(wsb + OIH_OFF), (u16*)(wsb + OIL_OFF),
        (float*)(wsb + LV_OFF));

    scale_attn_kernel<<<dim3(65536), dim3(256), 0, stream>>>(
        attnbuf, (const float*)(wsb + LV_OFF));

    oproj_mfma_kernel<<<dim3(32, 8, 2), dim3(256), 0, stream>>>(
        wsb, Wo, bo, out);
}

// Round 10
// 370.058 us; speedup vs baseline: 2.0881x; 1.2000x over previous
//
#include <hip/hip_runtime.h>

typedef unsigned short u16;
typedef unsigned int   u32;
typedef __attribute__((ext_vector_type(4)))  u16   us4;
typedef __attribute__((ext_vector_type(8)))  u16   us8;
typedef __attribute__((ext_vector_type(8)))  short s8v;
typedef __attribute__((ext_vector_type(16))) float f32x16;

#define L_   2048
#define D_   512
#define H_   8
#define PE_  2097152ull      // B*L*D elements of one fp32 projection array

// ---- ws layout (bytes) ----
//  [0 .. 32MB)   : 8 bf16 mats (QRH,QRL,QIH,QIL,KRH,KRL,KIH,KIL), each [bh][i][64]
//  [32 .. 40MB)  : 2 bf16 mats VTR,VTI, each [bh][dh][2048]  (V transposed)
//  [40 .. 56MB)  : o splits: ORH,ORL,OIH,OIL bf16 [4096][512]
//  [56MB ..]     : l (32768 fp32)
#define MATE    2097152ull   // u16 elems per mat
#define BHE     131072u      // u16 elems per (bh) slice of a mat (2048*64)
#define VT_OFF  33554432ull
#define ORH_OFF 41943040ull
#define ORL_OFF 46137344ull
#define OIH_OFF 50331648ull
#define OIL_OFF 54525952ull
#define LV_OFF  58720256ull

// ---- d_out scratch (bytes from out base; inside attnbuf, dead before attn writes) ----
#define XRH_O 16777216ull
#define XRL_O 20971520ull
#define XIH_O 25165824ull
#define XIL_O 29360128ull

#define MFMA32(a,b,c) __builtin_amdgcn_mfma_f32_32x32x16_bf16(a,b,c,0,0,0)
#define ROWOF(r,hi) (((r)&3) + 8*((r)>>2) + 4*(hi))

__device__ __forceinline__ u16 f2bf(float x){
    u32 u = __float_as_uint(x);
    u += 0x7FFFu + ((u>>16)&1u);
    return (u16)(u>>16);
}
__device__ __forceinline__ float bf2f(u16 h){ return __uint_as_float(((u32)h)<<16); }

// ============================================================
// Prep: split wave_real / wave_imag into bf16 hi/lo mats (d_out scratch)
// ============================================================
__global__ __launch_bounds__(256)
void split_prep_kernel(const float* __restrict__ wr, const float* __restrict__ wi,
                       unsigned char* __restrict__ outb)
{
    const int z = blockIdx.y;
    const float* src = z ? wi : wr;
    u16* hg = (u16*)(outb + (z ? XIH_O : XRH_O));
    u16* lg = (u16*)(outb + (z ? XIL_O : XRL_O));
    const size_t idx4 = ((size_t)blockIdx.x * 256 + threadIdx.x) * 4;
    float4 v = *(const float4*)&src[idx4];
    float vv[4] = { v.x, v.y, v.z, v.w };
    us4 h, l;
    #pragma unroll
    for (int c = 0; c < 4; ++c) {
        u16 hb = f2bf(vv[c]);
        h[c] = hb;
        l[c] = f2bf(vv[c] - bf2f(hb));
    }
    *(us4*)&hg[idx4] = h;
    *(us4*)&lg[idx4] = l;
}

// ============================================================
// LDS helpers (XOR swizzle byte ^= (row&7)<<4, both sides)
// ============================================================
__device__ __forceinline__ s8v ldfrag(const unsigned char* Lp, u32 matOff, u32 row, u32 colb)
{
    return *(const s8v*)(Lp + matOff + row*128u + (colb ^ ((row&7u)<<4)));
}
__device__ __forceinline__ void stage_qk(unsigned char* Lp, u32 matOff,
                                         const u16* __restrict__ g, int rowBase, int tid)
{
    const int ch = tid & 7;
    const int r0 = tid >> 3;
    #pragma unroll
    for (int rr = 0; rr < 2; ++rr) {
        u32 row = rr*32 + r0;
        us8 v = ((const us8*)(g + (size_t)(rowBase + row)*64))[ch];
        *(us8*)(Lp + matOff + row*128u + (((u32)ch<<4) ^ ((row&7u)<<4))) = v;
    }
}
__device__ __forceinline__ void stage_vt(unsigned char* Lp, u32 matOff,
                                         const u16* __restrict__ g, int j0, int tid, bool neg)
{
    const int ch = tid & 7;
    const int r0 = tid >> 3;
    #pragma unroll
    for (int rr = 0; rr < 2; ++rr) {
        u32 dh = rr*32 + r0;
        us8 v = ((const us8*)(g + (size_t)dh*2048 + j0))[ch];
        if (neg) v = v ^ (u16)0x8000u;
        *(us8*)(Lp + matOff + dh*128u + (((u32)ch<<4) ^ ((dh&7u)<<4))) = v;
    }
}

// ============================================================
// MFMA projection: C = X @ W^T + b for 6 combos. (unchanged, proven)
// ============================================================
__global__ __launch_bounds__(256, 2)
void proj_mfma_kernel(const unsigned char* __restrict__ scr,
                      const float* __restrict__ Wq, const float* __restrict__ Wk,
                      const float* __restrict__ Wv,
                      const float* __restrict__ bq, const float* __restrict__ bk,
                      const float* __restrict__ bv,
                      u16* __restrict__ qk, u16* __restrict__ vt)
{
    const int z = blockIdx.z;
    const u16* Ah_g = (const u16*)(scr + ((z & 1) ? XIH_O : XRH_O));
    const u16* Al_g = (const u16*)(scr + ((z & 1) ? XIL_O : XRL_O));
    const int wsel = z >> 1;
    const float* Wf; const float* bias;
    if (wsel == 0)      { Wf = Wq; bias = bq; }
    else if (wsel == 1) { Wf = Wk; bias = bk; }
    else                { Wf = Wv; bias = bv; }
    const bool four = (wsel < 2);

    const int m0 = blockIdx.x * 128;
    const int n0 = blockIdx.y * 64;

    __shared__ __align__(16) unsigned char L[49152];
    enum : u32 { AH=0, AL=16384, BH=32768, BL=40960 };

    const int tid  = threadIdx.x;
    const int lane = tid & 63;
    const int wid  = tid >> 6;
    const int wr   = wid >> 1, wc = wid & 1;
    const int l31  = lane & 31;
    const int hi   = lane >> 5;
    const u32 rowA0 = (u32)(wr*64 + l31);
    const u32 rowB  = (u32)(wc*32 + l31);

    f32x16 c0, c1;
    #pragma unroll
    for (int r = 0; r < 16; ++r) { c0[r] = 0.f; c1[r] = 0.f; }

    const int ch = tid & 7, r0 = tid >> 3;

    for (int k0 = 0; k0 < 512; k0 += 64) {
        __syncthreads();
        #pragma unroll
        for (int rr = 0; rr < 4; ++rr) {
            u32 row = (u32)(rr*32 + r0);
            u32 dst = row*128u + (((u32)ch<<4) ^ ((row&7u)<<4));
            us8 vh = *(const us8*)(Ah_g + (size_t)(m0 + row)*512 + k0 + ch*8);
            *(us8*)(L + AH + dst) = vh;
            if (four) {
                us8 vl = *(const us8*)(Al_g + (size_t)(m0 + row)*512 + k0 + ch*8);
                *(us8*)(L + AL + dst) = vl;
            }
        }
        #pragma unroll
        for (int rr = 0; rr < 2; ++rr) {
            u32 row = (u32)(rr*32 + r0);
            const float* src = Wf + (size_t)(n0 + row)*512 + k0 + ch*8;
            float4 v0 = *(const float4*)src;
            float4 v1 = *(const float4*)(src + 4);
            float vv[8] = { v0.x,v0.y,v0.z,v0.w, v1.x,v1.y,v1.z,v1.w };
            us8 hv, lv;
            #pragma unroll
            for (int j = 0; j < 8; ++j) {
                u16 hb = f2bf(vv[j]);
                hv[j] = hb;
                lv[j] = f2bf(vv[j] - bf2f(hb));
            }
            u32 dst = row*128u + (((u32)ch<<4) ^ ((row&7u)<<4));
            *(us8*)(L + BH + dst) = hv;
            if (four) *(us8*)(L + BL + dst) = lv;
        }
        __syncthreads();

        #pragma unroll
        for (int ks = 0; ks < 4; ++ks) {
            u32 colb = (u32)(ks*32 + hi*16);
            s8v a0h = ldfrag(L, AH, rowA0,      colb);
            s8v a1h = ldfrag(L, AH, rowA0 + 32, colb);
            s8v bh_ = ldfrag(L, BH, rowB,       colb);
            c0 = MFMA32(a0h, bh_, c0);
            c1 = MFMA32(a1h, bh_, c1);
            if (four) {
                s8v a0l = ldfrag(L, AL, rowA0,      colb);
                s8v a1l = ldfrag(L, AL, rowA0 + 32, colb);
                s8v bl_ = ldfrag(L, BL, rowB,       colb);
                c0 = MFMA32(a0h, bl_, c0); c0 = MFMA32(a0l, bh_, c0); c0 = MFMA32(a0l, bl_, c0);
                c1 = MFMA32(a1h, bl_, c1); c1 = MFMA32(a1l, bh_, c1); c1 = MFMA32(a1l, bl_, c1);
            }
        }
    }

    const int n  = n0 + wc*32 + l31;
    const float bvv = bias[n];
    const int h  = n >> 6, dh = n & 63;

    if (z < 4) {
        u16* hg = qk + (size_t)(2*z)   * MATE;
        u16* lg = qk + (size_t)(2*z+1) * MATE;
        #pragma unroll
        for (int f = 0; f < 2; ++f) {
            const f32x16& c = f ? c1 : c0;
            #pragma unroll
            for (int r = 0; r < 16; ++r) {
                int m  = m0 + wr*64 + 32*f + ROWOF(r, hi);
                int b_ = m >> 11, i = m & 2047;
                size_t idx = (size_t)(b_*8 + h)*BHE + (size_t)i*64 + dh;
                float v = c[r] + bvv;
                u16 hb = f2bf(v);
                hg[idx] = hb;
                lg[idx] = f2bf(v - bf2f(hb));
            }
        }
    } else {
        u16* vg = vt + (size_t)(z & 1) * MATE;
        #pragma unroll
        for (int f = 0; f < 2; ++f) {
            const f32x16& c = f ? c1 : c0;
            #pragma unroll
            for (int g = 0; g < 4; ++g) {
                int mb = m0 + wr*64 + 32*f + 8*g + 4*hi;
                int b_ = mb >> 11, ib = mb & 2047;
                us4 pv;
                #pragma unroll
                for (int j = 0; j < 4; ++j) pv[j] = f2bf(c[4*g + j] + bvv);
                *(us4*)&vg[(size_t)(b_*8 + h)*BHE + (size_t)dh*2048 + ib] = pv;
            }
        }
    }
}

// ============================================================
// MFMA attention — exact R3 champion structure (Q resident in LDS,
// 3-accumulator QK, sweep2 4 barriers/jt, V staged after QK hidden
// under pointwise). Deltas vs R3: sweep1 does 2 j-tiles per barrier
// pair (KRL/KIL slots free in sweep1); setprio around MFMA clusters;
// 1-mul pointwise micro-opt. LDS 80 KB (2 blocks/CU exactly).
// ============================================================
__global__ __launch_bounds__(256, 2)
void attn_mfma_kernel(const u16* __restrict__ qk,
                      const u16* __restrict__ vt,
                      float* __restrict__ attnbuf,
                      u16* __restrict__ orh, u16* __restrict__ orl,
                      u16* __restrict__ oih, u16* __restrict__ oil,
                      float* __restrict__ l_out)
{
    const int bh = blockIdx.x;
    const int i0 = blockIdx.y * 64;
    const int tid  = threadIdx.x;
    const int lane = tid & 63;
    const int wid  = tid >> 6;
    const int wr   = wid >> 1, wc = wid & 1;
    const int l31  = lane & 31;
    const int hi   = lane >> 5;
    const u32 rowA = wr*32 + l31;
    const u32 rowB = wc*32 + l31;

    __shared__ __align__(16) unsigned char L[81920];
    enum : u32 { QRH=0, QRL=8192, QIH=16384, QIL=24576,
                 KRH=32768, KRL=40960, KIH=49152, KIL=57344,
                 VRo=32768, VIo=40960, VNo=49152,
                 PAC=65536, PAS=73728 };

    const u16* qrh = qk + 0*MATE + (size_t)bh*BHE;
    const u16* qrl = qk + 1*MATE + (size_t)bh*BHE;
    const u16* qih = qk + 2*MATE + (size_t)bh*BHE;
    const u16* qil = qk + 3*MATE + (size_t)bh*BHE;
    const u16* krh = qk + 4*MATE + (size_t)bh*BHE;
    const u16* krl = qk + 5*MATE + (size_t)bh*BHE;
    const u16* kih = qk + 6*MATE + (size_t)bh*BHE;
    const u16* kil = qk + 7*MATE + (size_t)bh*BHE;
    const u16* vtr = vt + 0*MATE + (size_t)bh*BHE;
    const u16* vti = vt + 1*MATE + (size_t)bh*BHE;

    // stage Q (once, resident)
    stage_qk(L, QRH, qrh, i0, tid);
    stage_qk(L, QRL, qrl, i0, tid);
    stage_qk(L, QIH, qih, i0, tid);
    stage_qk(L, QIL, qil, i0, tid);

    // ---------------- sweep 1: approx row max (hi*hi only) ----------------
    // 2 j-tiles per barrier pair: K(2p) -> KRH/KIH, K(2p+1) -> KRL/KIL.
    float mxv[16];
    #pragma unroll
    for (int r = 0; r < 16; ++r) mxv[r] = 0.f;

    for (int jp = 0; jp < 16; ++jp) {
        __syncthreads();
        stage_qk(L, KRH, krh, (2*jp)*64,     tid);
        stage_qk(L, KIH, kih, (2*jp)*64,     tid);
        stage_qk(L, KRL, krh, (2*jp+1)*64,   tid);
        stage_qk(L, KIL, kih, (2*jp+1)*64,   tid);
        __syncthreads();
        __builtin_amdgcn_s_setprio(1);
        #pragma unroll
        for (int half = 0; half < 2; ++half) {
            const u32 kR = half ? KRL : KRH;
            const u32 kI = half ? KIL : KIH;
            f32x16 ir, ip, in_;
            #pragma unroll
            for (int r = 0; r < 16; ++r) { ir[r]=0.f; ip[r]=0.f; in_[r]=0.f; }
            #pragma unroll
            for (int ks = 0; ks < 4; ++ks) {
                u32 colb = ks*32 + hi*16;
                s8v aR = ldfrag(L, QRH, rowA, colb);
                s8v aI = ldfrag(L, QIH, rowA, colb);
                s8v bR = ldfrag(L, kR,  rowB, colb);
                s8v bI = ldfrag(L, kI,  rowB, colb);
                ir  = MFMA32(aR, bR, ir);
                ir  = MFMA32(aI, bI, ir);
                ip  = MFMA32(aR, bI, ip);
                in_ = MFMA32(aI, bR, in_);
            }
            #pragma unroll
            for (int r = 0; r < 16; ++r) {
                float xr = ir[r], xi = ip[r] - in_[r];
                float q = xr*xr + xi*xi;
                mxv[r] = fmaxf(mxv[r], q * 0.125f);
            }
        }
        __builtin_amdgcn_s_setprio(0);
    }
    #pragma unroll
    for (int m = 1; m < 32; m <<= 1)
        #pragma unroll
        for (int r = 0; r < 16; ++r) mxv[r] = fmaxf(mxv[r], __shfl_xor(mxv[r], m));

    // cross-wave (wc) combine via scratch in P region
    float* sc = (float*)(L + PAC);
    __syncthreads();
    #pragma unroll
    for (int r = 0; r < 16; ++r)
        if (l31 == r) sc[wc*64 + wr*32 + ROWOF(r,hi)] = mxv[r];
    __syncthreads();
    float mfin[16];
    #pragma unroll
    for (int r = 0; r < 16; ++r) {
        u32 row = wr*32 + ROWOF(r,hi);
        mfin[r] = fmaxf(sc[row], sc[64 + row]);
    }

    // ---------------- sweep 2 ----------------
    f32x16 ore, oim;
    float lp[16];
    #pragma unroll
    for (int r = 0; r < 16; ++r) { ore[r]=0.f; oim[r]=0.f; lp[r]=0.f; }

    for (int jt = 0; jt < 32; ++jt) {
        const int j0 = jt * 64;
        __syncthreads();                       // prev PV done; K/V/P free
        stage_qk(L, KRH, krh, j0, tid);
        stage_qk(L, KRL, krl, j0, tid);
        stage_qk(L, KIH, kih, j0, tid);
        stage_qk(L, KIL, kil, j0, tid);
        __syncthreads();

        f32x16 ir, ip, in_;
        #pragma unroll
        for (int r = 0; r < 16; ++r) { ir[r]=0.f; ip[r]=0.f; in_[r]=0.f; }
        __builtin_amdgcn_s_setprio(1);
        #pragma unroll
        for (int ks = 0; ks < 4; ++ks) {
            u32 colb = ks*32 + hi*16;
            s8v aRH = ldfrag(L, QRH, rowA, colb);
            s8v aRL = ldfrag(L, QRL, rowA, colb);
            s8v aIH = ldfrag(L, QIH, rowA, colb);
            s8v aIL = ldfrag(L, QIL, rowA, colb);
            s8v bRH = ldfrag(L, KRH, rowB, colb);
            s8v bRL = ldfrag(L, KRL, rowB, colb);
            s8v bIH = ldfrag(L, KIH, rowB, colb);
            s8v bIL = ldfrag(L, KIL, rowB, colb);
            ir = MFMA32(aRH, bRH, ir); ir = MFMA32(aRH, bRL, ir); ir = MFMA32(aRL, bRH, ir);
            ir = MFMA32(aIH, bIH, ir); ir = MFMA32(aIH, bIL, ir); ir = MFMA32(aIL, bIH, ir);
            ip  = MFMA32(aRH, bIH, ip);  ip  = MFMA32(aRH, bIL, ip);  ip  = MFMA32(aRL, bIH, ip);
            in_ = MFMA32(aIH, bRH, in_); in_ = MFMA32(aIH, bRL, in_); in_ = MFMA32(aIL, bRH, in_);
        }
        __builtin_amdgcn_s_setprio(0);
        __syncthreads();                       // all K reads done -> overwrite with V
        stage_vt(L, VRo, vtr, j0, tid, false);
        stage_vt(L, VIo, vti, j0, tid, false);
        stage_vt(L, VNo, vti, j0, tid, true);  // -Vi

        // pointwise: e, cos, sin; write attnbuf + P LDS (hides V loads)
        float* arow = attnbuf + (size_t)bh*4194304ull + (size_t)i0*2048 + j0 + wc*32 + l31;
        #pragma unroll
        for (int r = 0; r < 16; ++r) {
            float xr = ir[r], xi = ip[r] - in_[r];
            float q  = fmaf(xr, xr, xi*xi);
            float e  = __expf(fmaf(q, 0.125f, -mfin[r]));
            lp[r] += e;
            float iv = rsqrtf(q);
            float t  = e * iv;
            float pc = (q > 0.f) ? xr*t : e;
            float ps = (q > 0.f) ? xi*t : 0.0f;
            u32 rowloc = wr*32 + ROWOF(r,hi);
            arow[(size_t)rowloc*2048] = e;
            u32 colb2 = (wc*32 + l31)*2;
            *(u16*)(L + PAC + rowloc*128u + (colb2 ^ ((rowloc&7u)<<4))) = f2bf(pc);
            *(u16*)(L + PAS + rowloc*128u + (colb2 ^ ((rowloc&7u)<<4))) = f2bf(ps);
        }
        __syncthreads();                       // V + P visible

        __builtin_amdgcn_s_setprio(1);
        #pragma unroll
        for (int ks = 0; ks < 4; ++ks) {
            u32 colb = ks*32 + hi*16;
            s8v aC = ldfrag(L, PAC, rowA, colb);
            s8v aS = ldfrag(L, PAS, rowA, colb);
            s8v vR = ldfrag(L, VRo, rowB, colb);
            s8v vI = ldfrag(L, VIo, rowB, colb);
            s8v vN = ldfrag(L, VNo, rowB, colb);
            ore = MFMA32(aC, vR, ore); ore = MFMA32(aS, vN, ore);
            oim = MFMA32(aS, vR, oim); oim = MFMA32(aC, vI, oim);
        }
        __builtin_amdgcn_s_setprio(0);
    }

    // ---------------- epilogue: l, normalize O, store splits ----------------
    #pragma unroll
    for (int m = 1; m < 32; m <<= 1)
        #pragma unroll
        for (int r = 0; r < 16; ++r) lp[r] += __shfl_xor(lp[r], m);

    __syncthreads();                           // last PV done -> reuse PAC scratch
    #pragma unroll
    for (int r = 0; r < 16; ++r)
        if (l31 == r) sc[wc*64 + wr*32 + ROWOF(r,hi)] = lp[r];
    __syncthreads();

    const int b_ = bh >> 3, h = bh & 7;
    const size_t cb = (size_t)h*64 + wc*32 + l31;
    #pragma unroll
    for (int r = 0; r < 16; ++r) {
        u32 row = wr*32 + ROWOF(r,hi);
        float ls = sc[row] + sc[64 + row];
        if (wc == 0 && l31 == 0) l_out[(size_t)bh*2048 + i0 + row] = ls;
        float inv = 1.0f / ls;
        size_t idx = ((size_t)b_*2048 + i0 + row)*512 + cb;
        float vr = ore[r] * inv;
        float vi = oim[r] * inv;
        u16 hr = f2bf(vr); orh[idx] = hr; orl[idx] = f2bf(vr - bf2f(hr));
        u16 hw = f2bf(vi); oih[idx] = hw; oil[idx] = f2bf(vi - bf2f(hw));
    }
}

// ============================================================
// attention *= 1/l[row]
// ============================================================
__global__ __launch_bounds__(256)
void scale_attn_kernel(float* __restrict__ attnbuf, const float* __restrict__ l)
{
    const size_t idx = (size_t)blockIdx.x * 256 + threadIdx.x;
    const size_t row = idx >> 9;
    const float inv = 1.f / l[row];
    float4* p = (float4*)attnbuf + idx;
    float4 v = *p;
    v.x *= inv; v.y *= inv; v.z *= inv; v.w *= inv;
    *p = v;
}

// ============================================================
// O projection: out = o @ Wo^T + bo, 3-term split-bf16 MFMA. (unchanged)
// ============================================================
__global__ __launch_bounds__(256, 2)
void oproj_mfma_kernel(const unsigned char* __restrict__ wsb,
                       const float* __restrict__ Wo, const float* __restrict__ bo,
                       float* __restrict__ out)
{
    const int z = blockIdx.z;
    const u16* Ah_g = (const u16*)(wsb + (z ? OIH_OFF : ORH_OFF));
    const u16* Al_g = (const u16*)(wsb + (z ? OIL_OFF : ORL_OFF));
    float* outp = out + (size_t)z * PE_;

    const int m0 = blockIdx.x * 128;
    const int n0 = blockIdx.y * 64;

    __shared__ __align__(16) unsigned char L[49152];
    enum : u32 { AH=0, AL=16384, BH=32768, BL=40960 };

    const int tid  = threadIdx.x;
    const int lane = tid & 63;
    const int wid  = tid >> 6;
    const int wr   = wid >> 1, wc = wid & 1;
    const int l31  = lane & 31;
    const int hi   = lane >> 5;
    const u32 rowA0 = (u32)(wr*64 + l31);
    const u32 rowB  = (u32)(wc*32 + l31);

    f32x16 c0, c1;
    #pragma unroll
    for (int r = 0; r < 16; ++r) { c0[r] = 0.f; c1[r] = 0.f; }

    const int ch = tid & 7, r0 = tid >> 3;

    for (int k0 = 0; k0 < 512; k0 += 64) {
        __syncthreads();
        #pragma unroll
        for (int rr = 0; rr < 4; ++rr) {
            u32 row = (u32)(rr*32 + r0);
            u32 dst = row*128u + (((u32)ch<<4) ^ ((row&7u)<<4));
            us8 vh = *(const us8*)(Ah_g + (size_t)(m0 + row)*512 + k0 + ch*8);
            us8 vl = *(const us8*)(Al_g + (size_t)(m0 + row)*512 + k0 + ch*8);
            *(us8*)(L + AH + dst) = vh;
            *(us8*)(L + AL + dst) = vl;
        }
        #pragma unroll
        for (int rr = 0; rr < 2; ++rr) {
            u32 row = (u32)(rr*32 + r0);
            const float* src = Wo + (size_t)(n0 + row)*512 + k0 + ch*8;
            float4 v0 = *(const float4*)src;
            float4 v1 = *(const float4*)(src + 4);
            float vv[8] = { v0.x,v0.y,v0.z,v0.w, v1.x,v1.y,v1.z,v1.w };
            us8 hv, lv;
            #pragma unroll
            for (int j = 0; j < 8; ++j) {
                u16 hb = f2bf(vv[j]);
                hv[j] = hb;
                lv[j] = f2bf(vv[j] - bf2f(hb));
            }
            u32 dst = row*128u + (((u32)ch<<4) ^ ((row&7u)<<4));
            *(us8*)(L + BH + dst) = hv;
            *(us8*)(L + BL + dst) = lv;
        }
        __syncthreads();

        #pragma unroll
        for (int ks = 0; ks < 4; ++ks) {
            u32 colb = (u32)(ks*32 + hi*16);
            s8v a0h = ldfrag(L, AH, rowA0,      colb);
            s8v a1h = ldfrag(L, AH, rowA0 + 32, colb);
            s8v a0l = ldfrag(L, AL, rowA0,      colb);
            s8v a1l = ldfrag(L, AL, rowA0 + 32, colb);
            s8v bh_ = ldfrag(L, BH, rowB,       colb);
            s8v bl_ = ldfrag(L, BL, rowB,       colb);
            c0 = MFMA32(a0h, bh_, c0); c0 = MFMA32(a0h, bl_, c0); c0 = MFMA32(a0l, bh_, c0);
            c1 = MFMA32(a1h, bh_, c1); c1 = MFMA32(a1h, bl_, c1); c1 = MFMA32(a1l, bh_, c1);
        }
    }

    const int n = n0 + wc*32 + l31;
    const float bvv = bo[n];
    #pragma unroll
    for (int f = 0; f < 2; ++f) {
        const f32x16& c = f ? c1 : c0;
        #pragma unroll
        for (int r = 0; r < 16; ++r) {
            int m = m0 + wr*64 + 32*f + ROWOF(r, hi);
            outp[(size_t)m*512 + n] = c[r] + bvv;
        }
    }
}

// ============================================================
extern "C" void kernel_launch(void* const* d_in, const int* in_sizes, int n_in,
                              void* d_out, int out_size, void* d_ws, size_t ws_size,
                              hipStream_t stream)
{
    const float* wave_real = (const float*)d_in[0];
    const float* wave_imag = (const float*)d_in[1];
    const float* Wq = (const float*)d_in[2]; const float* bq = (const float*)d_in[3];
    const float* Wk = (const float*)d_in[4]; const float* bk = (const float*)d_in[5];
    const float* Wv = (const float*)d_in[6]; const float* bv = (const float*)d_in[7];
    const float* Wo = (const float*)d_in[8]; const float* bo = (const float*)d_in[9];
    float* out = (float*)d_out;
    unsigned char* outb = (unsigned char*)d_out;
    unsigned char* wsb  = (unsigned char*)d_ws;

    float* attnbuf = out + 2*PE_;

    split_prep_kernel<<<dim3(2048, 2), dim3(256), 0, stream>>>(wave_real, wave_imag, outb);

    proj_mfma_kernel<<<dim3(32, 8, 6), dim3(256), 0, stream>>>(
        outb, Wq, Wk, Wv, bq, bk, bv,
        (u16*)wsb, (u16*)(wsb + VT_OFF));

    attn_mfma_kernel<<<dim3(16, 32), dim3(256), 0, stream>>>(
        (const u16*)wsb, (const u16*)(wsb + VT_OFF), attnbuf,
        (u16*)(wsb + ORH_OFF), (u16*)(wsb + ORL_OFF),
        (u16*)(wsb + OIH_OFF), (u16*)(wsb + OIL_OFF),
        (float*)(wsb + LV_OFF));

    scale_attn_kernel<<<dim3(65536), dim3(256), 0, stream>>>(
        attnbuf, (const float*)(wsb + LV_OFF));

    oproj_mfma_kernel<<<dim3(32, 8, 2), dim3(256), 0, stream>>>(
        wsb, Wo, bo, out);
}